// Round 13
// baseline (29.593 us; speedup 1.0000x reference)
//
#include <hip/hip_runtime.h>

// Problem constants (match reference)
#define BQ 32
#define TT 20000
#define NN 200
#define S3 600              // 3*N
#define JSTRIDE 296         // lds halfs per j (288 + 8 pad; keeps 16B align, spreads banks)
#define R_HALFS ((size_t)NN * NN * 288)      // 11,520,000 halfs = 23.04 MB

typedef float    f32x4 __attribute__((ext_vector_type(4)));
typedef _Float16 f16x8 __attribute__((ext_vector_type(8)));   // 16B
typedef _Float16 f16x4 __attribute__((ext_vector_type(4)));   // 8B

// ---------------------------------------------------------------------------
// Kernel 1: streaming repack, vector-LDS both phases.
// Block = (i, jh): covers rows 3i..3i+2, cols 300*jh..300*jh+299, ALL 32 b.
// Load: per task (b-quad, p, c4) 4x f32x4 from 4 batches (1.2KB runs each),
//       in-register transpose -> ds_write_b64 of f16x4 (b-quad packed).
// LDS layout = final [j_local][pq][32b] -> store phase is ds_read_b128 +
//       one fully-contiguous 57.6KB global chunk.
// ---------------------------------------------------------------------------
__global__ __launch_bounds__(512) void repack3_kernel(
    const float* __restrict__ H, _Float16* __restrict__ R)
{
    __shared__ _Float16 lds[100 * JSTRIDE];   // 59,200 B
    const int i   = blockIdx.x >> 1;
    const int jh  = blockIdx.x & 1;
    const int tid = threadIdx.x;

    // 1800 tasks = bq(8) x p(3) x c4(75)
    for (int e = tid; e < 1800; e += 512) {
        int bq  = e / 225;
        int rem = e - bq * 225;
        int p   = rem / 75;
        int c4  = rem - p * 75;
        const float* base = H + (size_t)(3 * i + p) * S3 + jh * 300 + 4 * c4;
        f32x4 v0 = *reinterpret_cast<const f32x4*>(base + (size_t)(bq * 4 + 0) * (S3 * S3));
        f32x4 v1 = *reinterpret_cast<const f32x4*>(base + (size_t)(bq * 4 + 1) * (S3 * S3));
        f32x4 v2 = *reinterpret_cast<const f32x4*>(base + (size_t)(bq * 4 + 2) * (S3 * S3));
        f32x4 v3 = *reinterpret_cast<const f32x4*>(base + (size_t)(bq * 4 + 3) * (S3 * S3));
#pragma unroll
        for (int x = 0; x < 4; ++x) {
            int cl = 4 * c4 + x;                 // local col 0..299
            int jl = cl / 3, q = cl - 3 * jl;    // j_local, q
            f16x4 hv;
            hv[0] = (_Float16)v0[x];
            hv[1] = (_Float16)v1[x];
            hv[2] = (_Float16)v2[x];
            hv[3] = (_Float16)v3[x];
            *reinterpret_cast<f16x4*>(&lds[jl * JSTRIDE + (p * 3 + q) * 32 + bq * 4]) = hv;
        }
    }
    __syncthreads();

    // 3600 f16x8: jl(100) x (pq*4+h)(36); contiguous global stores.
    f16x8* dst = reinterpret_cast<f16x8*>(R + ((size_t)i * NN + jh * 100) * 288);
    for (int w = tid; w < 3600; w += 512) {
        int jl  = w / 36;
        int rem = w - jl * 36;                   // pq*4 + h
        f16x8 v = *reinterpret_cast<const f16x8*>(&lds[jl * JSTRIDE + rem * 8]);
        dst[(size_t)jl * 36 + rem] = v;
    }
}

// ---------------------------------------------------------------------------
// Shared compute: four distinct products T2[u][v] = Mij * S^u * Mjk * S^v * Mki
// (S = diag(1,1,-1)); all 8 Frobenius errors derived from them.
// ---------------------------------------------------------------------------
__device__ __forceinline__ void compute_errs(
    const float Mij[9], const float Mjk[9], const float Mki[9], float res[8])
{
    float N1[2][9];
#pragma unroll
    for (int p = 0; p < 3; ++p) {
#pragma unroll
        for (int r = 0; r < 3; ++r) {
            float c = Mij[p*3+0] * Mjk[0*3+r] + Mij[p*3+1] * Mjk[1*3+r];
            float d = Mij[p*3+2] * Mjk[2*3+r];
            N1[0][p*3+r] = c + d;
            N1[1][p*3+r] = c - d;
        }
    }
    float err[2][2];
#pragma unroll
    for (int u = 0; u < 2; ++u) {
        float T2p[9], T2m[9];
#pragma unroll
        for (int p = 0; p < 3; ++p) {
#pragma unroll
            for (int s = 0; s < 3; ++s) {
                float c = N1[u][p*3+0] * Mki[0*3+s] + N1[u][p*3+1] * Mki[1*3+s];
                float d = N1[u][p*3+2] * Mki[2*3+s];
                T2p[p*3+s] = c + d;
                T2m[p*3+s] = c - d;
            }
        }
#pragma unroll
        for (int v = 0; v < 2; ++v) {
            const float* T2 = (v == 0) ? T2p : T2m;
            float ss = 0.0f;
#pragma unroll
            for (int e = 0; e < 9; ++e) ss += T2[e] * T2[e];
            float diag = T2[0] + T2[4] + (((u ^ v) & 1) ? -T2[8] : T2[8]);
            float e2 = ss - 2.0f * diag + 3.0f;
            err[u][v] = sqrtf(fmaxf(e2, 0.0f));
        }
    }
#pragma unroll
    for (int m = 0; m < 8; ++m) {
        int a = (m >> 2) & 1, bb = (m >> 1) & 1, c = m & 1;
        res[m] = err[a ^ bb][bb ^ c];
    }
}

// ---------------------------------------------------------------------------
// Kernel 2: gather (R6 layout). 8 lanes/t, f16x4 loads, 4 batches/thread.
// Per (t,pq) load instr: 8 lanes consume one fully-dense 64B line.
// ---------------------------------------------------------------------------
__global__ __launch_bounds__(256, 2) void gather4_kernel(
    const _Float16* __restrict__ R, const int* __restrict__ trip,
    float* __restrict__ out)
{
    int g  = blockIdx.x * 256 + threadIdx.x;   // 160000 threads exactly
    int bg = g & 7;
    int t  = g >> 3;

    int i = trip[3 * t + 0];
    int j = trip[3 * t + 1];
    int k = trip[3 * t + 2];

    const f16x4* __restrict__ Rij = reinterpret_cast<const f16x4*>(R) + (size_t)(i * NN + j) * 72 + bg;
    const f16x4* __restrict__ Rjk = reinterpret_cast<const f16x4*>(R) + (size_t)(j * NN + k) * 72 + bg;
    const f16x4* __restrict__ Rki = reinterpret_cast<const f16x4*>(R) + (size_t)(k * NN + i) * 72 + bg;

    f16x4 Aij[9], Ajk[9], Aki[9];
#pragma unroll
    for (int pq = 0; pq < 9; ++pq) {
        Aij[pq] = Rij[pq * 8];
        Ajk[pq] = Rjk[pq * 8];
        Aki[pq] = Rki[pq * 8];
    }

#pragma unroll
    for (int u = 0; u < 4; ++u) {
        float Mij[9], Mjk[9], Mki[9];
#pragma unroll
        for (int pq = 0; pq < 9; ++pq) {
            Mij[pq] = (float)Aij[pq][u];
            Mjk[pq] = (float)Ajk[pq][u];
            Mki[pq] = (float)Aki[pq][u];
        }
        float res[8];
        compute_errs(Mij, Mjk, Mki, res);

        int b = 4 * bg + u;
        f32x4* o4 = reinterpret_cast<f32x4*>(out + ((size_t)b * TT + t) * 8);
        f32x4 lo, hi;
        lo.x = res[0]; lo.y = res[1]; lo.z = res[2]; lo.w = res[3];
        hi.x = res[4]; hi.y = res[5]; hi.z = res[6]; hi.w = res[7];
        __builtin_nontemporal_store(lo, o4);
        __builtin_nontemporal_store(hi, o4 + 1);
    }
}

// ---------------------------------------------------------------------------
// Fallback (direct kernel) in case ws is too small for R.
// ---------------------------------------------------------------------------
__global__ __launch_bounds__(256) void jcfg_err_direct(
    const float* __restrict__ H,
    const int*   __restrict__ trip,
    float*       __restrict__ out)
{
    int idx = blockIdx.x * blockDim.x + threadIdx.x;
    if (idx >= BQ * TT) return;
    int b = idx / TT;
    int t = idx - b * TT;

    int i = trip[3 * t + 0];
    int j = trip[3 * t + 1];
    int k = trip[3 * t + 2];

    const float* __restrict__ Hb = H + (size_t)b * (S3 * S3);

    float Mij[9], Mjk[9], Mki[9];
    const int ri = 3 * i, rj = 3 * j, rk = 3 * k;
#pragma unroll
    for (int p = 0; p < 3; ++p) {
        __builtin_memcpy(&Mij[3*p], Hb + (size_t)(ri + p) * S3 + rj, 12);
        __builtin_memcpy(&Mjk[3*p], Hb + (size_t)(rj + p) * S3 + rk, 12);
        __builtin_memcpy(&Mki[3*p], Hb + (size_t)(rk + p) * S3 + ri, 12);
    }

    float res[8];
    compute_errs(Mij, Mjk, Mki, res);

    float* o = out + (size_t)idx * 8;
    *reinterpret_cast<float4*>(o)     = make_float4(res[0], res[1], res[2], res[3]);
    *reinterpret_cast<float4*>(o + 4) = make_float4(res[4], res[5], res[6], res[7]);
}

extern "C" void kernel_launch(void* const* d_in, const int* in_sizes, int n_in,
                              void* d_out, int out_size, void* d_ws, size_t ws_size,
                              hipStream_t stream)
{
    const float* H    = (const float*)d_in[0];
    const int*   trip = (const int*)d_in[1];
    float*       out  = (float*)d_out;

    if (ws_size >= R_HALFS * sizeof(_Float16)) {
        _Float16* R = (_Float16*)d_ws;
        repack3_kernel<<<NN * 2, 512, 0, stream>>>(H, R);                  // 400 blocks
        gather4_kernel<<<(TT * 8) / 256, 256, 0, stream>>>(R, trip, out);  // 625 blocks
    } else {
        const int total = BQ * TT;
        jcfg_err_direct<<<(total + 255) / 256, 256, 0, stream>>>(H, trip, out);
    }
}

// Round 14
// 29.189 us; speedup vs baseline: 1.0138x; 1.0138x over previous
//
#include <hip/hip_runtime.h>

// Problem constants (match reference)
#define BQ 32
#define TT 20000
#define NN 200
#define S3 600              // 3*N
#define JSTRIDE 296         // lds halfs per j (288 + 8 pad)
#define R_HALFS ((size_t)NN * NN * 288)      // 11,520,000 halfs = 23.04 MB

typedef float    f32x4 __attribute__((ext_vector_type(4)));
typedef float    f32x2 __attribute__((ext_vector_type(2)));
typedef _Float16 f16x8 __attribute__((ext_vector_type(8)));   // 16B
typedef _Float16 f16x4 __attribute__((ext_vector_type(4)));   // 8B

// ---------------------------------------------------------------------------
// Kernel 1: streaming repack (identical to R13's repack3).
// ---------------------------------------------------------------------------
__global__ __launch_bounds__(512) void repack3_kernel(
    const float* __restrict__ H, _Float16* __restrict__ R)
{
    __shared__ _Float16 lds[100 * JSTRIDE];   // 59,200 B
    const int i   = blockIdx.x >> 1;
    const int jh  = blockIdx.x & 1;
    const int tid = threadIdx.x;

    for (int e = tid; e < 1800; e += 512) {
        int bq  = e / 225;
        int rem = e - bq * 225;
        int p   = rem / 75;
        int c4  = rem - p * 75;
        const float* base = H + (size_t)(3 * i + p) * S3 + jh * 300 + 4 * c4;
        f32x4 v0 = *reinterpret_cast<const f32x4*>(base + (size_t)(bq * 4 + 0) * (S3 * S3));
        f32x4 v1 = *reinterpret_cast<const f32x4*>(base + (size_t)(bq * 4 + 1) * (S3 * S3));
        f32x4 v2 = *reinterpret_cast<const f32x4*>(base + (size_t)(bq * 4 + 2) * (S3 * S3));
        f32x4 v3 = *reinterpret_cast<const f32x4*>(base + (size_t)(bq * 4 + 3) * (S3 * S3));
#pragma unroll
        for (int x = 0; x < 4; ++x) {
            int cl = 4 * c4 + x;
            int jl = cl / 3, q = cl - 3 * jl;
            f16x4 hv;
            hv[0] = (_Float16)v0[x];
            hv[1] = (_Float16)v1[x];
            hv[2] = (_Float16)v2[x];
            hv[3] = (_Float16)v3[x];
            *reinterpret_cast<f16x4*>(&lds[jl * JSTRIDE + (p * 3 + q) * 32 + bq * 4]) = hv;
        }
    }
    __syncthreads();

    f16x8* dst = reinterpret_cast<f16x8*>(R + ((size_t)i * NN + jh * 100) * 288);
    for (int w = tid; w < 3600; w += 512) {
        int jl  = w / 36;
        int rem = w - jl * 36;
        f16x8 v = *reinterpret_cast<const f16x8*>(&lds[jl * JSTRIDE + rem * 8]);
        dst[(size_t)jl * 36 + rem] = v;
    }
}

// ---------------------------------------------------------------------------
// Packed compute: two batches per call in the two f32 lanes of f32x2.
// Same math as the scalar version -> bit-identical results per lane
// (packed v_pk_fma_f32 == scalar v_fma_f32 per component).
// ---------------------------------------------------------------------------
__device__ __forceinline__ f32x2 pk_sqrt_clamp(f32x2 x)
{
    f32x2 r;
    r.x = sqrtf(fmaxf(x.x, 0.0f));
    r.y = sqrtf(fmaxf(x.y, 0.0f));
    return r;
}

__device__ __forceinline__ void compute_errs_pk(
    const f32x2 Mij[9], const f32x2 Mjk[9], const f32x2 Mki[9], f32x2 res[8])
{
    f32x2 N1[2][9];
#pragma unroll
    for (int p = 0; p < 3; ++p) {
#pragma unroll
        for (int r = 0; r < 3; ++r) {
            f32x2 c = Mij[p*3+0] * Mjk[0*3+r] + Mij[p*3+1] * Mjk[1*3+r];
            f32x2 d = Mij[p*3+2] * Mjk[2*3+r];
            N1[0][p*3+r] = c + d;
            N1[1][p*3+r] = c - d;
        }
    }
    f32x2 err[2][2];
#pragma unroll
    for (int u = 0; u < 2; ++u) {
        f32x2 T2p[9], T2m[9];
#pragma unroll
        for (int p = 0; p < 3; ++p) {
#pragma unroll
            for (int s = 0; s < 3; ++s) {
                f32x2 c = N1[u][p*3+0] * Mki[0*3+s] + N1[u][p*3+1] * Mki[1*3+s];
                f32x2 d = N1[u][p*3+2] * Mki[2*3+s];
                T2p[p*3+s] = c + d;
                T2m[p*3+s] = c - d;
            }
        }
#pragma unroll
        for (int v = 0; v < 2; ++v) {
            const f32x2* T2 = (v == 0) ? T2p : T2m;
            f32x2 ss = T2[0] * T2[0];
#pragma unroll
            for (int e = 1; e < 9; ++e) ss += T2[e] * T2[e];
            f32x2 diag = T2[0] + T2[4] + (((u ^ v) & 1) ? -T2[8] : T2[8]);
            f32x2 e2 = ss - 2.0f * diag + 3.0f;
            err[u][v] = pk_sqrt_clamp(e2);
        }
    }
#pragma unroll
    for (int m = 0; m < 8; ++m) {
        int a = (m >> 2) & 1, bb = (m >> 1) & 1, c = m & 1;
        res[m] = err[a ^ bb][bb ^ c];
    }
}

// ---------------------------------------------------------------------------
// Kernel 2: gather, packed-f32x2 compute. 8 lanes/t, f16x4 loads,
// 4 batches/thread processed as 2 packed pairs.
// ---------------------------------------------------------------------------
__global__ __launch_bounds__(256, 2) void gather4_pk_kernel(
    const _Float16* __restrict__ R, const int* __restrict__ trip,
    float* __restrict__ out)
{
    int g  = blockIdx.x * 256 + threadIdx.x;   // 160000 threads exactly
    int bg = g & 7;
    int t  = g >> 3;

    int i = trip[3 * t + 0];
    int j = trip[3 * t + 1];
    int k = trip[3 * t + 2];

    const f16x4* __restrict__ Rij = reinterpret_cast<const f16x4*>(R) + (size_t)(i * NN + j) * 72 + bg;
    const f16x4* __restrict__ Rjk = reinterpret_cast<const f16x4*>(R) + (size_t)(j * NN + k) * 72 + bg;
    const f16x4* __restrict__ Rki = reinterpret_cast<const f16x4*>(R) + (size_t)(k * NN + i) * 72 + bg;

    f16x4 Aij[9], Ajk[9], Aki[9];
#pragma unroll
    for (int pq = 0; pq < 9; ++pq) {
        Aij[pq] = Rij[pq * 8];
        Ajk[pq] = Rjk[pq * 8];
        Aki[pq] = Rki[pq * 8];
    }

#pragma unroll
    for (int h = 0; h < 2; ++h) {              // packed pair: batches 2h, 2h+1
        f32x2 Mij[9], Mjk[9], Mki[9];
#pragma unroll
        for (int pq = 0; pq < 9; ++pq) {
            Mij[pq] = f32x2{(float)Aij[pq][2*h], (float)Aij[pq][2*h+1]};
            Mjk[pq] = f32x2{(float)Ajk[pq][2*h], (float)Ajk[pq][2*h+1]};
            Mki[pq] = f32x2{(float)Aki[pq][2*h], (float)Aki[pq][2*h+1]};
        }
        f32x2 r2[8];
        compute_errs_pk(Mij, Mjk, Mki, r2);

#pragma unroll
        for (int u2 = 0; u2 < 2; ++u2) {
            int b = 4 * bg + 2 * h + u2;
            f32x4* o4 = reinterpret_cast<f32x4*>(out + ((size_t)b * TT + t) * 8);
            f32x4 lo, hi;
            lo.x = r2[0][u2]; lo.y = r2[1][u2]; lo.z = r2[2][u2]; lo.w = r2[3][u2];
            hi.x = r2[4][u2]; hi.y = r2[5][u2]; hi.z = r2[6][u2]; hi.w = r2[7][u2];
            __builtin_nontemporal_store(lo, o4);
            __builtin_nontemporal_store(hi, o4 + 1);
        }
    }
}

// ---------------------------------------------------------------------------
// Scalar compute (fallback path only)
// ---------------------------------------------------------------------------
__device__ __forceinline__ void compute_errs(
    const float Mij[9], const float Mjk[9], const float Mki[9], float res[8])
{
    float N1[2][9];
#pragma unroll
    for (int p = 0; p < 3; ++p) {
#pragma unroll
        for (int r = 0; r < 3; ++r) {
            float c = Mij[p*3+0] * Mjk[0*3+r] + Mij[p*3+1] * Mjk[1*3+r];
            float d = Mij[p*3+2] * Mjk[2*3+r];
            N1[0][p*3+r] = c + d;
            N1[1][p*3+r] = c - d;
        }
    }
    float err[2][2];
#pragma unroll
    for (int u = 0; u < 2; ++u) {
        float T2p[9], T2m[9];
#pragma unroll
        for (int p = 0; p < 3; ++p) {
#pragma unroll
            for (int s = 0; s < 3; ++s) {
                float c = N1[u][p*3+0] * Mki[0*3+s] + N1[u][p*3+1] * Mki[1*3+s];
                float d = N1[u][p*3+2] * Mki[2*3+s];
                T2p[p*3+s] = c + d;
                T2m[p*3+s] = c - d;
            }
        }
#pragma unroll
        for (int v = 0; v < 2; ++v) {
            const float* T2 = (v == 0) ? T2p : T2m;
            float ss = 0.0f;
#pragma unroll
            for (int e = 0; e < 9; ++e) ss += T2[e] * T2[e];
            float diag = T2[0] + T2[4] + (((u ^ v) & 1) ? -T2[8] : T2[8]);
            float e2 = ss - 2.0f * diag + 3.0f;
            err[u][v] = sqrtf(fmaxf(e2, 0.0f));
        }
    }
#pragma unroll
    for (int m = 0; m < 8; ++m) {
        int a = (m >> 2) & 1, bb = (m >> 1) & 1, c = m & 1;
        res[m] = err[a ^ bb][bb ^ c];
    }
}

// ---------------------------------------------------------------------------
// Fallback (direct kernel) in case ws is too small for R.
// ---------------------------------------------------------------------------
__global__ __launch_bounds__(256) void jcfg_err_direct(
    const float* __restrict__ H,
    const int*   __restrict__ trip,
    float*       __restrict__ out)
{
    int idx = blockIdx.x * blockDim.x + threadIdx.x;
    if (idx >= BQ * TT) return;
    int b = idx / TT;
    int t = idx - b * TT;

    int i = trip[3 * t + 0];
    int j = trip[3 * t + 1];
    int k = trip[3 * t + 2];

    const float* __restrict__ Hb = H + (size_t)b * (S3 * S3);

    float Mij[9], Mjk[9], Mki[9];
    const int ri = 3 * i, rj = 3 * j, rk = 3 * k;
#pragma unroll
    for (int p = 0; p < 3; ++p) {
        __builtin_memcpy(&Mij[3*p], Hb + (size_t)(ri + p) * S3 + rj, 12);
        __builtin_memcpy(&Mjk[3*p], Hb + (size_t)(rj + p) * S3 + rk, 12);
        __builtin_memcpy(&Mki[3*p], Hb + (size_t)(rk + p) * S3 + ri, 12);
    }

    float res[8];
    compute_errs(Mij, Mjk, Mki, res);

    float* o = out + (size_t)idx * 8;
    *reinterpret_cast<float4*>(o)     = make_float4(res[0], res[1], res[2], res[3]);
    *reinterpret_cast<float4*>(o + 4) = make_float4(res[4], res[5], res[6], res[7]);
}

extern "C" void kernel_launch(void* const* d_in, const int* in_sizes, int n_in,
                              void* d_out, int out_size, void* d_ws, size_t ws_size,
                              hipStream_t stream)
{
    const float* H    = (const float*)d_in[0];
    const int*   trip = (const int*)d_in[1];
    float*       out  = (float*)d_out;

    if (ws_size >= R_HALFS * sizeof(_Float16)) {
        _Float16* R = (_Float16*)d_ws;
        repack3_kernel<<<NN * 2, 512, 0, stream>>>(H, R);                     // 400 blocks
        gather4_pk_kernel<<<(TT * 8) / 256, 256, 0, stream>>>(R, trip, out);  // 625 blocks
    } else {
        const int total = BQ * TT;
        jcfg_err_direct<<<(total + 255) / 256, 256, 0, stream>>>(H, trip, out);
    }
}